// Round 3
// baseline (27.919 us; speedup 1.0000x reference)
//
#include <hip/hip_runtime.h>

#define RR 300
#define NCLS 37
#define COUT 36
#define NW 10          // 300 bits -> 10 u32 words per mask row
#define NWAVE 5
#define SCORE_THR_C 0.1f
#define NMS_THR_C 0.4f
#define NB 32

// ws layout: box4 [B][COUT][RR] float4, then score [B][COUT][RR] float
#define WS_BOX_ELEMS ((size_t)NB * COUT * RR)
#define WS_NEED_BYTES (WS_BOX_ELEMS * (sizeof(float4) + sizeof(float)))

// ===================== Kernel A: coalesced decode + transpose =====================
// block = 288 threads = 36 classes x 8 rois-rows; grid = 32 batches x 38 row-blocks.
// Grid index arranged so batch b's blocks land on XCD b/4 (matches NMS swizzle).
__global__ __launch_bounds__(288) void decode_kernel(
    const float* __restrict__ rois,
    const float* __restrict__ pred,
    const float* __restrict__ scr,
    const float* __restrict__ iminfo,
    float4* __restrict__ box_ws,
    float*  __restrict__ scr_ws)
{
#pragma clang fp contract(off)
    const int bid = blockIdx.x;
    const int xcd = bid & 7;          // == b/4
    const int rem = bid >> 3;         // rb + 38*(b%4)
    const int bm  = rem / 38;
    const int rb  = rem % 38;
    const int b   = xcd * 4 + bm;

    const int t   = threadIdx.x;
    const int c   = t % 36;
    const int rr  = t / 36;
    const int r   = rb * 8 + rr;
    if (r >= RR) return;
    const int cls = c + 1;

    const float4 ro = *reinterpret_cast<const float4*>(rois + (size_t)(b * RR + r) * 4);
    float w  = ro.z - ro.x + 1.0f;
    float h  = ro.w - ro.y + 1.0f;
    float cx = ro.x + 0.5f * w;
    float cy = ro.y + 0.5f * h;
    const float4 pp = *reinterpret_cast<const float4*>(
        pred + (size_t)(b * RR + r) * (4 * NCLS) + 4 * cls);
    float dx = pp.x * 0.1f;
    float dy = pp.y * 0.1f;
    float dw = pp.z * 0.2f;
    float dh = pp.w * 0.2f;
    float pcx = dx * w + cx;
    float pcy = dy * h + cy;
    float pw  = expf(dw) * w;
    float ph  = expf(dh) * h;
    float Hm1 = iminfo[b * 3 + 0] - 1.0f;
    float Wm1 = iminfo[b * 3 + 1] - 1.0f;
    float sc  = iminfo[2];   // im_info[0, 2] for ALL batches (per reference)
    float4 bx;
    bx.x = fminf(fmaxf(pcx - 0.5f * pw, 0.0f), Wm1) / sc;
    bx.y = fminf(fmaxf(pcy - 0.5f * ph, 0.0f), Hm1) / sc;
    bx.z = fminf(fmaxf(pcx + 0.5f * pw, 0.0f), Wm1) / sc;
    bx.w = fminf(fmaxf(pcy + 0.5f * ph, 0.0f), Hm1) / sc;

    const size_t o = ((size_t)b * COUT + c) * RR + r;
    box_ws[o] = bx;
    scr_ws[o] = scr[(size_t)(b * RR + r) * NCLS + cls];
}

// ===================== Kernel B: per-(b,c) NMS from L2/L3-hot ws =====================
__global__ __launch_bounds__(320) void nms_kernel(
    const float4* __restrict__ box_ws,
    const float*  __restrict__ scr_ws,
    float* __restrict__ out)
{
#pragma clang fp contract(off)
    const int bid = blockIdx.x;
    const int bc  = (bid & 7) * 144 + (bid >> 3);   // 1152 = 8 * 144; batch b -> XCD b/4
    const int b   = bc / COUT;
    const int c   = bc % COUT;
    const int tid = threadIdx.x;
    const int lane = tid & 63;
    const int wid  = tid >> 6;

    __shared__ float        cscore[RR + 4];
    __shared__ float4       sbox[RR];
    __shared__ float        sar[RR];
    __shared__ int          sorig[RR];
    __shared__ unsigned int mask[RR * NW];
    __shared__ unsigned char keepS[RR];
    __shared__ unsigned char keepG[RR];
    __shared__ int          wcnt[NWAVE];
    __shared__ int          top_sh;

    // ---- contiguous, cache-hot loads ----
    float4 box = make_float4(0.f, 0.f, 0.f, 0.f);
    float  score = 0.f, area = 0.f;
    if (tid < RR) {
        const size_t o = ((size_t)b * COUT + c) * RR + tid;
        box   = box_ws[o];
        score = scr_ws[o];
        area  = (box.z - box.x) * (box.w - box.y);
        keepS[tid] = 0;
        keepG[tid] = 0;
    }

    // ---- validity ballot + cross-wave prefix sum ----
    const bool v = (tid < RR) && (score > SCORE_THR_C);
    unsigned long long bal = __ballot(v);
    int inw = __popcll(bal & ((1ull << lane) - 1ull));
    if (lane == 0) wcnt[wid] = __popcll(bal);
    __syncthreads();

    int pos = inw, nvl = 0;
    #pragma unroll
    for (int w = 0; w < NWAVE; ++w) {
        int cw = wcnt[w];
        nvl += cw;
        if (w < wid) pos += cw;
    }
    const int nv = nvl;

    if (v) cscore[pos] = score;
    if (tid < 4) cscore[nv + tid] = -1.0f;
    __syncthreads();

    // ---- stable descending rank among nv valid elems ----
    int rank = 0;
    if (v) {
        const float4* cs4 = reinterpret_cast<const float4*>(cscore);
        const int n4 = (nv + 3) >> 2;
        const float si = score;
        for (int q4 = 0; q4 < n4; ++q4) {
            float4 sv = cs4[q4];
            int qb = q4 * 4;
            rank += (int)(sv.x > si) + ((int)(sv.x == si) & (int)(qb + 0 < pos));
            rank += (int)(sv.y > si) + ((int)(sv.y == si) & (int)(qb + 1 < pos));
            rank += (int)(sv.z > si) + ((int)(sv.z == si) & (int)(qb + 2 < pos));
            rank += (int)(sv.w > si) + ((int)(sv.w == si) & (int)(qb + 3 < pos));
        }
    }
    __syncthreads();
    if (v) {
        sbox[rank]  = box;
        sar[rank]   = area;
        sorig[rank] = tid;
    }
    __syncthreads();

    // ---- suppression bitmask rows among top-nv ----
    if (tid < nv) {
        const float4 bi = sbox[tid];
        const float  ai = sar[tid];
        unsigned int m[NW];
        #pragma unroll
        for (int w = 0; w < NW; ++w) m[w] = 0u;
        for (int j = tid + 1; j < nv; ++j) {
            float4 bj = sbox[j];
            float lx = fmaxf(bi.x, bj.x);
            float ly = fmaxf(bi.y, bj.y);
            float rx = fminf(bi.z, bj.z);
            float ry = fminf(bi.w, bj.w);
            float iw = fmaxf(rx - lx, 0.0f);
            float ih = fmaxf(ry - ly, 0.0f);
            float inter = iw * ih;
            float den = ai + sar[j] - inter + 1e-12f;
            float iou = inter / den;
            if (iou > NMS_THR_C) m[j >> 5] |= (1u << (j & 31));
        }
        #pragma unroll
        for (int w = 0; w < NW; ++w) mask[tid * NW + w] = m[w];
    }
    __syncthreads();

    // ---- serial greedy scan ----
    if (tid == 0) {
        unsigned long long live[5];
        #pragma unroll
        for (int w = 0; w < 5; ++w) {
            int lo = w * 64;
            if (nv >= lo + 64)      live[w] = ~0ull;
            else if (nv <= lo)      live[w] = 0ull;
            else                    live[w] = (~0ull) >> (64 - (nv - lo));
        }
        int first = -1;
        for (;;) {
            int i = -1;
            #pragma unroll
            for (int w = 0; w < 5; ++w) {
                if (live[w]) { i = w * 64 + __builtin_ctzll(live[w]); break; }
            }
            if (i < 0) break;
            keepS[i] = 1;
            if (first < 0) first = i;
            live[i >> 6] &= ~(1ull << (i & 63));
            const unsigned int* mr = &mask[i * NW];
            #pragma unroll
            for (int w = 0; w < 5; ++w) {
                unsigned long long mm = (unsigned long long)mr[2 * w] |
                                        ((unsigned long long)mr[2 * w + 1] << 32);
                live[w] &= ~mm;
            }
        }
        top_sh = first;
    }
    __syncthreads();

    if (tid < nv) {
        bool k = (c == 0) ? (tid == top_sh) : (keepS[tid] != 0);
        if (k) keepG[sorig[tid]] = 1;
    }
    __syncthreads();

    if (tid < RR) {
        float k = keepG[tid] ? 1.0f : 0.0f;
        size_t base = (((size_t)b * COUT + c) * RR + tid) * 5;
        out[base + 0] = fmaxf(box.x, 0.0f) * k;
        out[base + 1] = fmaxf(box.y, 0.0f) * k;
        out[base + 2] = fmaxf(box.z, 0.0f) * k;
        out[base + 3] = fmaxf(box.w, 0.0f) * k;
        out[base + 4] = fmaxf(score, 0.0f) * k;
    }
}

// ===================== Fallback: monolithic (R2) in case ws is too small =====================
__global__ __launch_bounds__(320) void det_nms_kernel(
    const float* __restrict__ rois,
    const float* __restrict__ pred,
    const float* __restrict__ scr,
    const float* __restrict__ iminfo,
    float* __restrict__ out)
{
#pragma clang fp contract(off)
    const int bid = blockIdx.x;
    const int bc  = (bid & 7) * 144 + (bid >> 3);
    const int b   = bc / COUT;
    const int c   = bc % COUT;
    const int cls = c + 1;
    const int tid = threadIdx.x;
    const int lane = tid & 63;
    const int wid  = tid >> 6;

    __shared__ float        cscore[RR + 4];
    __shared__ float4       sbox[RR];
    __shared__ float        sar[RR];
    __shared__ int          sorig[RR];
    __shared__ unsigned int mask[RR * NW];
    __shared__ unsigned char keepS[RR];
    __shared__ unsigned char keepG[RR];
    __shared__ int          wcnt[NWAVE];
    __shared__ int          top_sh;

    float4 box = make_float4(0.f, 0.f, 0.f, 0.f);
    float  score = 0.f, area = 0.f;
    if (tid < RR) {
        const float4 ro = *reinterpret_cast<const float4*>(rois + (size_t)(b * RR + tid) * 4);
        float w  = ro.z - ro.x + 1.0f;
        float h  = ro.w - ro.y + 1.0f;
        float cx = ro.x + 0.5f * w;
        float cy = ro.y + 0.5f * h;
        const float4 pp = *reinterpret_cast<const float4*>(
            pred + (size_t)(b * RR + tid) * (4 * NCLS) + 4 * cls);
        float dx = pp.x * 0.1f;
        float dy = pp.y * 0.1f;
        float dw = pp.z * 0.2f;
        float dh = pp.w * 0.2f;
        float pcx = dx * w + cx;
        float pcy = dy * h + cy;
        float pw  = expf(dw) * w;
        float ph  = expf(dh) * h;
        float Hm1 = iminfo[b * 3 + 0] - 1.0f;
        float Wm1 = iminfo[b * 3 + 1] - 1.0f;
        float sc  = iminfo[2];
        box.x = fminf(fmaxf(pcx - 0.5f * pw, 0.0f), Wm1) / sc;
        box.y = fminf(fmaxf(pcy - 0.5f * ph, 0.0f), Hm1) / sc;
        box.z = fminf(fmaxf(pcx + 0.5f * pw, 0.0f), Wm1) / sc;
        box.w = fminf(fmaxf(pcy + 0.5f * ph, 0.0f), Hm1) / sc;
        score = scr[(size_t)(b * RR + tid) * NCLS + cls];
        area  = (box.z - box.x) * (box.w - box.y);
        keepS[tid] = 0;
        keepG[tid] = 0;
    }

    const bool v = (tid < RR) && (score > SCORE_THR_C);
    unsigned long long bal = __ballot(v);
    int inw = __popcll(bal & ((1ull << lane) - 1ull));
    if (lane == 0) wcnt[wid] = __popcll(bal);
    __syncthreads();

    int pos = inw, nvl = 0;
    #pragma unroll
    for (int w = 0; w < NWAVE; ++w) {
        int cw = wcnt[w];
        nvl += cw;
        if (w < wid) pos += cw;
    }
    const int nv = nvl;

    if (v) cscore[pos] = score;
    if (tid < 4) cscore[nv + tid] = -1.0f;
    __syncthreads();

    int rank = 0;
    if (v) {
        const float4* cs4 = reinterpret_cast<const float4*>(cscore);
        const int n4 = (nv + 3) >> 2;
        const float si = score;
        for (int q4 = 0; q4 < n4; ++q4) {
            float4 sv = cs4[q4];
            int qb = q4 * 4;
            rank += (int)(sv.x > si) + ((int)(sv.x == si) & (int)(qb + 0 < pos));
            rank += (int)(sv.y > si) + ((int)(sv.y == si) & (int)(qb + 1 < pos));
            rank += (int)(sv.z > si) + ((int)(sv.z == si) & (int)(qb + 2 < pos));
            rank += (int)(sv.w > si) + ((int)(sv.w == si) & (int)(qb + 3 < pos));
        }
    }
    __syncthreads();
    if (v) {
        sbox[rank]  = box;
        sar[rank]   = area;
        sorig[rank] = tid;
    }
    __syncthreads();

    if (tid < nv) {
        const float4 bi = sbox[tid];
        const float  ai = sar[tid];
        unsigned int m[NW];
        #pragma unroll
        for (int w = 0; w < NW; ++w) m[w] = 0u;
        for (int j = tid + 1; j < nv; ++j) {
            float4 bj = sbox[j];
            float lx = fmaxf(bi.x, bj.x);
            float ly = fmaxf(bi.y, bj.y);
            float rx = fminf(bi.z, bj.z);
            float ry = fminf(bi.w, bj.w);
            float iw = fmaxf(rx - lx, 0.0f);
            float ih = fmaxf(ry - ly, 0.0f);
            float inter = iw * ih;
            float den = ai + sar[j] - inter + 1e-12f;
            float iou = inter / den;
            if (iou > NMS_THR_C) m[j >> 5] |= (1u << (j & 31));
        }
        #pragma unroll
        for (int w = 0; w < NW; ++w) mask[tid * NW + w] = m[w];
    }
    __syncthreads();

    if (tid == 0) {
        unsigned long long live[5];
        #pragma unroll
        for (int w = 0; w < 5; ++w) {
            int lo = w * 64;
            if (nv >= lo + 64)      live[w] = ~0ull;
            else if (nv <= lo)      live[w] = 0ull;
            else                    live[w] = (~0ull) >> (64 - (nv - lo));
        }
        int first = -1;
        for (;;) {
            int i = -1;
            #pragma unroll
            for (int w = 0; w < 5; ++w) {
                if (live[w]) { i = w * 64 + __builtin_ctzll(live[w]); break; }
            }
            if (i < 0) break;
            keepS[i] = 1;
            if (first < 0) first = i;
            live[i >> 6] &= ~(1ull << (i & 63));
            const unsigned int* mr = &mask[i * NW];
            #pragma unroll
            for (int w = 0; w < 5; ++w) {
                unsigned long long mm = (unsigned long long)mr[2 * w] |
                                        ((unsigned long long)mr[2 * w + 1] << 32);
                live[w] &= ~mm;
            }
        }
        top_sh = first;
    }
    __syncthreads();

    if (tid < nv) {
        bool k = (c == 0) ? (tid == top_sh) : (keepS[tid] != 0);
        if (k) keepG[sorig[tid]] = 1;
    }
    __syncthreads();

    if (tid < RR) {
        float k = keepG[tid] ? 1.0f : 0.0f;
        size_t base = (((size_t)b * COUT + c) * RR + tid) * 5;
        out[base + 0] = fmaxf(box.x, 0.0f) * k;
        out[base + 1] = fmaxf(box.y, 0.0f) * k;
        out[base + 2] = fmaxf(box.z, 0.0f) * k;
        out[base + 3] = fmaxf(box.w, 0.0f) * k;
        out[base + 4] = fmaxf(score, 0.0f) * k;
    }
}

extern "C" void kernel_launch(void* const* d_in, const int* in_sizes, int n_in,
                              void* d_out, int out_size, void* d_ws, size_t ws_size,
                              hipStream_t stream) {
    const float* rois   = (const float*)d_in[0];
    const float* pred   = (const float*)d_in[1];
    const float* scores = (const float*)d_in[2];
    const float* iminfo = (const float*)d_in[3];
    float* out = (float*)d_out;

    if (ws_size >= WS_NEED_BYTES) {
        float4* box_ws = (float4*)d_ws;
        float*  scr_ws = (float*)((char*)d_ws + WS_BOX_ELEMS * sizeof(float4));
        decode_kernel<<<dim3(NB * 38), dim3(288), 0, stream>>>(
            rois, pred, scores, iminfo, box_ws, scr_ws);
        nms_kernel<<<dim3(NB * COUT), dim3(320), 0, stream>>>(box_ws, scr_ws, out);
    } else {
        det_nms_kernel<<<dim3(NB * COUT), dim3(320), 0, stream>>>(
            rois, pred, scores, iminfo, out);
    }
}